// Round 1
// baseline (1070.061 us; speedup 1.0000x reference)
//
#include <hip/hip_runtime.h>

// ---------------------------------------------------------------------------
// SVT channel/token mixing: dwconv (ch 0..63) + DTCWT fwd -> channel mix ->
// token mix -> DTCWT inv (ch 64..127).  B=256, H=W=28, C=128, Ch=64.
// Layouts: all spatial intermediates are [b][h][w][c] with c (64) fastest
// (one wave = 64 lanes = one channel slice -> perfectly coalesced).
// Band buffer: [b][band(6)][h2][w2][c], real & imag in separate arrays.
// ---------------------------------------------------------------------------

#define DI __device__ __forceinline__

__constant__ float c_h0[13] = {
  -0.0017578f, 0.0f, 0.0222656f, -0.046875f, -0.0482422f, 0.296875f,
   0.5554688f, 0.296875f, -0.0482422f, -0.046875f, 0.0222656f, 0.0f, -0.0017578f};
__constant__ float c_h1[19] = {
  -7.06e-05f, 0.0f, 0.0013419f, -0.0018834f, -0.0071568f, 0.023856f,
   0.0556431f, -0.0516881f, -0.2997576f, 0.5594308f, -0.2997576f, -0.0516881f,
   0.0556431f, 0.023856f, -0.0071568f, -0.0018834f, 0.0013419f, 0.0f, -7.06e-05f};
// g0 = h1 * sgn19 (sgn=+1 for odd idx), g1 = -(h0 * sgn13) (sgn=+1 for even idx)
__constant__ float c_g0[19] = {
   7.06e-05f, 0.0f, -0.0013419f, -0.0018834f, 0.0071568f, 0.023856f,
  -0.0556431f, -0.0516881f, 0.2997576f, 0.5594308f, 0.2997576f, -0.0516881f,
  -0.0556431f, 0.023856f, 0.0071568f, -0.0018834f, -0.0013419f, 0.0f, 7.06e-05f};
__constant__ float c_g1[13] = {
   0.0017578f, 0.0f, -0.0222656f, -0.046875f, 0.0482422f, 0.296875f,
  -0.5554688f, 0.296875f, 0.0482422f, -0.046875f, -0.0222656f, 0.0f, 0.0017578f};

DI int refl28(int i) { return i < 0 ? -1 - i : (i >= 28 ? 55 - i : i); }

// ---------------- K1: depthwise 3x3 conv (zero pad), channels 0..63 --------
__global__ __launch_bounds__(256) void k_dwconv(const float* __restrict__ x,
    const float* __restrict__ cw, const float* __restrict__ cb,
    float* __restrict__ out) {
  int tid = blockIdx.x * 256 + threadIdx.x;
  int c = tid & 63;
  int s = tid >> 6;                 // b*784 + h*28 + w
  int w = s % 28; int t2 = s / 28; int h = t2 % 28; int b = t2 / 28; (void)b;
  const float* k = cw + c * 9;
  const float* xb = x + (size_t)s * 128 + c;
  float acc = cb[c];
  bool hm = h > 0, hp = h < 27, wm = w > 0, wp = w < 27;
  if (hm) {
    const float* r = xb - 28 * 128;
    if (wm) acc = fmaf(r[-128], k[0], acc);
    acc = fmaf(r[0], k[1], acc);
    if (wp) acc = fmaf(r[128], k[2], acc);
  }
  if (wm) acc = fmaf(xb[-128], k[3], acc);
  acc = fmaf(xb[0], k[4], acc);
  if (wp) acc = fmaf(xb[128], k[5], acc);
  if (hp) {
    const float* r = xb + 28 * 128;
    if (wm) acc = fmaf(r[-128], k[6], acc);
    acc = fmaf(r[0], k[7], acc);
    if (wp) acc = fmaf(r[128], k[8], acc);
  }
  out[(size_t)s * 128 + c] = acc;
}

// ---------------- K2: row filter (along W) on x2 -> lo, hi -----------------
__global__ __launch_bounds__(256) void k_rowfilt(const float* __restrict__ x,
    float* __restrict__ lo, float* __restrict__ hi) {
  int tid = blockIdx.x * 256 + threadIdx.x;
  int c = tid & 63;
  int s = tid >> 6;
  int w = s % 28; int t2 = s / 28; int h = t2 % 28; int b = t2 / 28;
  const float* xr = x + ((size_t)(b * 784 + h * 28)) * 128 + 64 + c;
  float v[19];
#pragma unroll
  for (int j = 0; j < 19; j++) v[j] = xr[refl28(w - 9 + j) * 128];
  float aLo = 0.f, aHi = 0.f;
#pragma unroll
  for (int t = 0; t < 13; t++) aLo = fmaf(c_h0[t], v[t + 3], aLo);
#pragma unroll
  for (int t = 0; t < 19; t++) aHi = fmaf(c_h1[t], v[t], aHi);
  lo[(size_t)s * 64 + c] = aLo;
  hi[(size_t)s * 64 + c] = aHi;
}

// ------- K3: column filter (along H) + q2c -> xl (=ll*w_ll), bands ---------
__global__ __launch_bounds__(256) void k_colfilt(const float* __restrict__ lo,
    const float* __restrict__ hi, const float* __restrict__ wll,
    float* __restrict__ xl, float* __restrict__ xhr, float* __restrict__ xhi) {
  int tid = blockIdx.x * 256 + threadIdx.x;
  int c = tid & 63;
  int p = tid >> 6;                 // (b*14 + h2)*14 + w2
  int w2 = p % 14; int q = p / 14; int h2 = q % 14; int b = q / 14;
  float LH[2][2], HL[2][2], HH[2][2];   // [woff][hoff]
#pragma unroll
  for (int woff = 0; woff < 2; woff++) {
    int w = 2 * w2 + woff;
    float lov[20], hiv[20];
#pragma unroll
    for (int j = 0; j < 20; j++) {
      int r = refl28(2 * h2 - 9 + j);
      int off = (b * 784 + r * 28 + w) * 64 + c;
      lov[j] = lo[off];
      hiv[j] = hi[off];
    }
#pragma unroll
    for (int hoff = 0; hoff < 2; hoff++) {
      float vll = 0.f, vlh = 0.f, vhl = 0.f, vhh = 0.f;
#pragma unroll
      for (int t = 0; t < 13; t++) {
        vll = fmaf(c_h0[t], lov[hoff + t + 3], vll);
        vhl = fmaf(c_h0[t], hiv[hoff + t + 3], vhl);
      }
#pragma unroll
      for (int t = 0; t < 19; t++) {
        vlh = fmaf(c_h1[t], lov[hoff + t], vlh);
        vhh = fmaf(c_h1[t], hiv[hoff + t], vhh);
      }
      int h = 2 * h2 + hoff;
      xl[(b * 784 + h * 28 + w) * 64 + c] = vll * wll[c * 784 + h * 28 + w];
      LH[woff][hoff] = vlh; HL[woff][hoff] = vhl; HH[woff][hoff] = vhh;
    }
  }
  const float s2 = 0.70710678118654752f;
  int base = ((b * 6) * 196 + h2 * 14 + w2) * 64 + c;
  const int bstr = 196 * 64;
  // quad a=[w0][h0] b=[w1][h0] c=[w0][h1] d=[w1][h1]
  // bands: 0=lhp 1=hhp 2=hlp 3=hlq 4=hhq 5=lhq ; p=(a-d,b+c) q=(a+d,b-c)
  xhr[base + 0 * bstr] = (LH[0][0] - LH[1][1]) * s2;
  xhi[base + 0 * bstr] = (LH[1][0] + LH[0][1]) * s2;
  xhr[base + 5 * bstr] = (LH[0][0] + LH[1][1]) * s2;
  xhi[base + 5 * bstr] = (LH[1][0] - LH[0][1]) * s2;
  xhr[base + 2 * bstr] = (HL[0][0] - HL[1][1]) * s2;
  xhi[base + 2 * bstr] = (HL[1][0] + HL[0][1]) * s2;
  xhr[base + 3 * bstr] = (HL[0][0] + HL[1][1]) * s2;
  xhi[base + 3 * bstr] = (HL[1][0] - HL[0][1]) * s2;
  xhr[base + 1 * bstr] = (HH[0][0] - HH[1][1]) * s2;
  xhi[base + 1 * bstr] = (HH[1][0] + HH[0][1]) * s2;
  xhr[base + 4 * bstr] = (HH[0][0] + HH[1][1]) * s2;
  xhi[base + 4 * bstr] = (HH[1][0] - HH[0][1]) * s2;
}

// ---------------- K4a: complex block-diag channel mix (in place) -----------
__global__ __launch_bounds__(256) void k_chmix(float* __restrict__ xhr,
    float* __restrict__ xhi,
    const float* __restrict__ w1, const float* __restrict__ w2,
    const float* __restrict__ b1, const float* __restrict__ b2) {
  // LDS layout: (d*16+k)*8 + blk*2 + {0:r,1:i}  -> 4 distinct 8B addrs per
  // wave read (blk = lane&3), each broadcast to 16 lanes: conflict-free.
  __shared__ __align__(16) float sw1[2048];
  __shared__ __align__(16) float sw2[2048];
  __shared__ __align__(16) float sb1[128];
  __shared__ __align__(16) float sb2[128];
  int tid = threadIdx.x;
  for (int i = tid; i < 1024; i += 256) {
    int dk = i >> 2, blk = i & 3;
    int li = dk * 8 + blk * 2;
    sw1[li]     = w1[blk * 256 + dk];
    sw1[li + 1] = w1[1024 + blk * 256 + dk];
    sw2[li]     = w2[blk * 256 + dk];
    sw2[li + 1] = w2[1024 + blk * 256 + dk];
  }
  if (tid < 64) {
    int k = tid >> 2, blk = tid & 3;
    int li = k * 8 + blk * 2;
    sb1[li] = b1[blk * 16 + k]; sb1[li + 1] = b1[64 + blk * 16 + k];
    sb2[li] = b2[blk * 16 + k]; sb2[li + 1] = b2[64 + blk * 16 + k];
  }
  __syncthreads();
  int idx = blockIdx.x * 256 + tid;
  int blk = idx & 3;
  int p = idx >> 2;                     // position in band-buffer order
  size_t base = (size_t)p * 64 + blk * 16;
  float xr[16], xi[16];
  const float4* pr = (const float4*)(xhr + base);
  const float4* pi = (const float4*)(xhi + base);
#pragma unroll
  for (int j = 0; j < 4; j++) {
    float4 a = pr[j];
    xr[4 * j] = a.x; xr[4 * j + 1] = a.y; xr[4 * j + 2] = a.z; xr[4 * j + 3] = a.w;
    float4 bb = pi[j];
    xi[4 * j] = bb.x; xi[4 * j + 1] = bb.y; xi[4 * j + 2] = bb.z; xi[4 * j + 3] = bb.w;
  }
  int wb = blk * 2;
  float yr[16], yi[16];
#pragma unroll
  for (int k = 0; k < 16; k++) {
    float2 bv = *(const float2*)(sb1 + k * 8 + wb);
    float ar = bv.x, ai = bv.y;
#pragma unroll
    for (int d = 0; d < 16; d++) {
      float2 wv = *(const float2*)(sw1 + (d * 16 + k) * 8 + wb);
      ar = fmaf(xr[d], wv.x, ar); ar = fmaf(-xi[d], wv.y, ar);
      ai = fmaf(xr[d], wv.y, ai); ai = fmaf(xi[d], wv.x, ai);
    }
    yr[k] = fmaxf(ar, 0.f); yi[k] = fmaxf(ai, 0.f);
  }
#pragma unroll
  for (int k = 0; k < 16; k++) {
    float2 bv = *(const float2*)(sb2 + k * 8 + wb);
    float ar = bv.x, ai = bv.y;
#pragma unroll
    for (int d = 0; d < 16; d++) {
      float2 wv = *(const float2*)(sw2 + (d * 16 + k) * 8 + wb);
      ar = fmaf(yr[d], wv.x, ar); ar = fmaf(-yi[d], wv.y, ar);
      ai = fmaf(yr[d], wv.y, ai); ai = fmaf(yi[d], wv.x, ai);
    }
    xr[k] = ar; xi[k] = ai;
  }
  float4* qr = (float4*)(xhr + base);
  float4* qi = (float4*)(xhi + base);
#pragma unroll
  for (int j = 0; j < 4; j++) {
    qr[j] = make_float4(xr[4 * j], xr[4 * j + 1], xr[4 * j + 2], xr[4 * j + 3]);
    qi[j] = make_float4(xi[4 * j], xi[4 * j + 1], xi[4 * j + 2], xi[4 * j + 3]);
  }
}

// ---------------- K4b: complex token mix over w2, per h2 (in place) --------
// 2 positions per thread (batch halves share h2) to amortize LDS weight reads.
__global__ __launch_bounds__(256) void k_tokmix(float* __restrict__ xhr,
    float* __restrict__ xhi,
    const float* __restrict__ wt1, const float* __restrict__ wt2,
    const float* __restrict__ bt1, const float* __restrict__ bt2) {
  __shared__ __align__(16) float st1[5488];   // (h2*196+d*14+k)*2 + {r,i}
  __shared__ __align__(16) float st2[5488];
  __shared__ __align__(16) float sB1[392];    // (h2*14+k)*2 + {r,i}
  __shared__ __align__(16) float sB2[392];
  int tid = threadIdx.x;
  for (int i = tid; i < 2744; i += 256) {
    st1[2 * i] = wt1[i]; st1[2 * i + 1] = wt1[2744 + i];
    st2[2 * i] = wt2[i]; st2[2 * i + 1] = wt2[2744 + i];
  }
  for (int i = tid; i < 196; i += 256) {
    sB1[2 * i] = bt1[i]; sB1[2 * i + 1] = bt1[196 + i];
    sB2[2 * i] = bt2[i]; sB2[2 * i + 1] = bt2[196 + i];
  }
  __syncthreads();
  int idx = blockIdx.x * 256 + tid;
  int c = idx & 63;
  int pp = idx >> 6;                  // [0,10752): pos A; pos B = pp+10752
  int h2 = pp % 14;
  int baseA = pp * 896 + c;           // 896 = 14*64
  int baseB = (pp + 10752) * 896 + c;
  float trA[14], tiA[14], trB[14], tiB[14];
#pragma unroll
  for (int d = 0; d < 14; d++) {
    trA[d] = xhr[baseA + d * 64]; tiA[d] = xhi[baseA + d * 64];
    trB[d] = xhr[baseB + d * 64]; tiB[d] = xhi[baseB + d * 64];
  }
  const float* w1 = st1 + h2 * 392;
  const float* w2 = st2 + h2 * 392;
  const float* bb1 = sB1 + h2 * 28;
  const float* bb2 = sB2 + h2 * 28;
  float mrA[14], miA[14], mrB[14], miB[14];
#pragma unroll
  for (int k = 0; k < 14; k++) {
    float br = bb1[2 * k], bi = bb1[2 * k + 1];
    float arA = br, aiA = bi, arB = br, aiB = bi;
#pragma unroll
    for (int d = 0; d < 14; d++) {
      float wr = w1[(d * 14 + k) * 2], wi = w1[(d * 14 + k) * 2 + 1];
      arA = fmaf(trA[d], wr, arA); arA = fmaf(-tiA[d], wi, arA);
      aiA = fmaf(trA[d], wi, aiA); aiA = fmaf(tiA[d], wr, aiA);
      arB = fmaf(trB[d], wr, arB); arB = fmaf(-tiB[d], wi, arB);
      aiB = fmaf(trB[d], wi, aiB); aiB = fmaf(tiB[d], wr, aiB);
    }
    mrA[k] = fmaxf(arA, 0.f); miA[k] = fmaxf(aiA, 0.f);
    mrB[k] = fmaxf(arB, 0.f); miB[k] = fmaxf(aiB, 0.f);
  }
#pragma unroll
  for (int k = 0; k < 14; k++) {
    float br = bb2[2 * k], bi = bb2[2 * k + 1];
    float arA = br, aiA = bi, arB = br, aiB = bi;
#pragma unroll
    for (int d = 0; d < 14; d++) {
      float wr = w2[(d * 14 + k) * 2], wi = w2[(d * 14 + k) * 2 + 1];
      arA = fmaf(mrA[d], wr, arA); arA = fmaf(-miA[d], wi, arA);
      aiA = fmaf(mrA[d], wi, aiA); aiA = fmaf(miA[d], wr, aiA);
      arB = fmaf(mrB[d], wr, arB); arB = fmaf(-miB[d], wi, arB);
      aiB = fmaf(mrB[d], wi, aiB); aiB = fmaf(miB[d], wr, aiB);
    }
    xhr[baseA + k * 64] = arA; xhi[baseA + k * 64] = aiA;
    xhr[baseB + k * 64] = arB; xhi[baseB + k * 64] = aiB;
  }
}

// -------- K5: inverse column filter (fused c2q from bands) -> lo2, hi2 -----
__global__ __launch_bounds__(256) void k_invcol(const float* __restrict__ xl,
    const float* __restrict__ xhr, const float* __restrict__ xhi,
    float* __restrict__ lo2, float* __restrict__ hi2) {
  int tid = blockIdx.x * 256 + threadIdx.x;
  int c = tid & 63;
  int s = tid >> 6;
  int w = s % 28; int t2 = s / 28; int h = t2 % 28; int b = t2 / 28;
  int j = w >> 1; int pw = w & 1;
  const float s2 = 0.70710678118654752f;
  int xbase = (b * 6 * 196 + j) * 64 + c;   // + band*12544 + i*896
  // lo = g0 * xl  +  g1 * c2q(band0, band5)
  float accLo = 0.f;
#pragma unroll
  for (int t = 0; t < 19; t++) {
    int r = refl28(h - 9 + t);
    accLo = fmaf(c_g0[t], xl[(b * 784 + r * 28 + w) * 64 + c], accLo);
  }
  float accB = 0.f;
#pragma unroll
  for (int t = 0; t < 13; t++) {
    int r = refl28(h - 6 + t);
    int i = r >> 1, ph = r & 1;
    const float* Y = (ph ^ pw) ? xhi : xhr;
    float y0 = Y[xbase + 0 * 12544 + i * 896];
    float y5 = Y[xbase + 5 * 12544 + i * 896];
    float v = ((ph & pw) ? -y0 : y0) + ((ph && !pw) ? -y5 : y5);
    accB = fmaf(c_g1[t], v, accB);
  }
  accLo = fmaf(accB, s2, accLo);
  // hi = g0 * c2q(band2, band3)  +  g1 * c2q(band1, band4)
  float accC = 0.f;
#pragma unroll
  for (int t = 0; t < 19; t++) {
    int r = refl28(h - 9 + t);
    int i = r >> 1, ph = r & 1;
    const float* Y = (ph ^ pw) ? xhi : xhr;
    float y0 = Y[xbase + 2 * 12544 + i * 896];
    float y5 = Y[xbase + 3 * 12544 + i * 896];
    float v = ((ph & pw) ? -y0 : y0) + ((ph && !pw) ? -y5 : y5);
    accC = fmaf(c_g0[t], v, accC);
  }
  float accD = 0.f;
#pragma unroll
  for (int t = 0; t < 13; t++) {
    int r = refl28(h - 6 + t);
    int i = r >> 1, ph = r & 1;
    const float* Y = (ph ^ pw) ? xhi : xhr;
    float y0 = Y[xbase + 1 * 12544 + i * 896];
    float y5 = Y[xbase + 4 * 12544 + i * 896];
    float v = ((ph & pw) ? -y0 : y0) + ((ph && !pw) ? -y5 : y5);
    accD = fmaf(c_g1[t], v, accD);
  }
  float accHi = (accC + accD) * s2;
  int o = s * 64 + c;
  lo2[o] = accLo;
  hi2[o] = accHi;
}

// ---------------- K6: inverse row filter -> output channels 64..127 --------
__global__ __launch_bounds__(256) void k_invrow(const float* __restrict__ lo2,
    const float* __restrict__ hi2, float* __restrict__ out) {
  int tid = blockIdx.x * 256 + threadIdx.x;
  int c = tid & 63;
  int s = tid >> 6;
  int w = s % 28; int t2 = s / 28; int h = t2 % 28; int b = t2 / 28;
  const float* lr = lo2 + (b * 784 + h * 28) * 64 + c;
  const float* hr = hi2 + (b * 784 + h * 28) * 64 + c;
  float acc = 0.f;
#pragma unroll
  for (int t = 0; t < 19; t++) acc = fmaf(c_g0[t], lr[refl28(w - 9 + t) * 64], acc);
#pragma unroll
  for (int t = 0; t < 13; t++) acc = fmaf(c_g1[t], hr[refl28(w - 6 + t) * 64], acc);
  out[(size_t)s * 128 + 64 + c] = acc;
}

// ---------------------------------------------------------------------------
extern "C" void kernel_launch(void* const* d_in, const int* in_sizes, int n_in,
                              void* d_out, int out_size, void* d_ws, size_t ws_size,
                              hipStream_t stream) {
  const float* x    = (const float*)d_in[0];
  const float* cw   = (const float*)d_in[1];
  const float* cb   = (const float*)d_in[2];
  const float* wll  = (const float*)d_in[3];
  const float* wlh1 = (const float*)d_in[4];
  const float* wlh2 = (const float*)d_in[5];
  const float* blh1 = (const float*)d_in[6];
  const float* blh2 = (const float*)d_in[7];
  const float* wt1  = (const float*)d_in[8];
  const float* wt2  = (const float*)d_in[9];
  const float* bt1  = (const float*)d_in[10];
  const float* bt2  = (const float*)d_in[11];
  float* out = (float*)d_out;
  float* ws = (float*)d_ws;

  const size_t NSP = (size_t)256 * 784 * 64;     // 12,845,056
  const size_t NXH = (size_t)256 * 6 * 196 * 64; // 19,267,584
  float* lo  = ws;              // reused as lo2 after k_colfilt consumes it
  float* hi  = lo + NSP;        // reused as hi2
  float* xl  = hi + NSP;
  float* xhr = xl + NSP;
  float* xhi = xhr + NXH;       // total 308.3 MB

  dim3 blk(256);
  k_dwconv <<<50176, blk, 0, stream>>>(x, cw, cb, out);
  k_rowfilt<<<50176, blk, 0, stream>>>(x, lo, hi);
  k_colfilt<<<12544, blk, 0, stream>>>(lo, hi, wll, xl, xhr, xhi);
  k_chmix  <<<4704,  blk, 0, stream>>>(xhr, xhi, wlh1, wlh2, blh1, blh2);
  k_tokmix <<<2688,  blk, 0, stream>>>(xhr, xhi, wt1, wt2, bt1, bt2);
  k_invcol <<<50176, blk, 0, stream>>>(xl, xhr, xhi, lo, hi);
  k_invrow <<<50176, blk, 0, stream>>>(lo, hi, out);
  (void)in_sizes; (void)n_in; (void)out_size; (void)ws_size;
}

// Round 2
// 694.433 us; speedup vs baseline: 1.5409x; 1.5409x over previous
//
#include <hip/hip_runtime.h>

// ---------------------------------------------------------------------------
// SVT channel/token mixing: dwconv (ch 0..63) + DTCWT fwd -> channel mix ->
// token mix -> DTCWT inv (ch 64..127).  B=256, H=W=28, C=128, Ch=64.
// Round 2: register-line filter kernels. One thread owns a full 28-sample
// line; loads it once into a register array; all tap indices are
// compile-time constants (refl28 folds away). Filters are constexpr ->
// literal operands. Each wave = one line (64 c lanes) -> wave-uniform
// parity branches, perfectly coalesced 256B accesses.
// ---------------------------------------------------------------------------

#define DI __device__ __forceinline__

__device__ constexpr float F_H0[13] = {
  -0.0017578f, 0.0f, 0.0222656f, -0.046875f, -0.0482422f, 0.296875f,
   0.5554688f, 0.296875f, -0.0482422f, -0.046875f, 0.0222656f, 0.0f, -0.0017578f};
__device__ constexpr float F_H1[19] = {
  -7.06e-05f, 0.0f, 0.0013419f, -0.0018834f, -0.0071568f, 0.023856f,
   0.0556431f, -0.0516881f, -0.2997576f, 0.5594308f, -0.2997576f, -0.0516881f,
   0.0556431f, 0.023856f, -0.0071568f, -0.0018834f, 0.0013419f, 0.0f, -7.06e-05f};
// g0 = h1 * sgn19 (+1 odd idx), g1 = -(h0 * sgn13) (+1 even idx)
__device__ constexpr float F_G0[19] = {
   7.06e-05f, 0.0f, -0.0013419f, -0.0018834f, 0.0071568f, 0.023856f,
  -0.0556431f, -0.0516881f, 0.2997576f, 0.5594308f, 0.2997576f, -0.0516881f,
  -0.0556431f, 0.023856f, 0.0071568f, -0.0018834f, -0.0013419f, 0.0f, 7.06e-05f};
__device__ constexpr float F_G1[13] = {
   0.0017578f, 0.0f, -0.0222656f, -0.046875f, 0.0482422f, 0.296875f,
  -0.5554688f, 0.296875f, 0.0482422f, -0.046875f, -0.0222656f, 0.0f, 0.0017578f};

DI constexpr int refl28(int i) { return i < 0 ? -1 - i : (i >= 28 ? 55 - i : i); }

#define S2C 0.70710678118654752f

// ---------------- K1: depthwise 3x3 conv (zero pad), channels 0..63 --------
__global__ __launch_bounds__(256) void k_dwconv(const float* __restrict__ x,
    const float* __restrict__ cw, const float* __restrict__ cb,
    float* __restrict__ out) {
  int tid = blockIdx.x * 256 + threadIdx.x;
  int c = tid & 63;
  int s = tid >> 6;                 // b*784 + h*28 + w
  int w = s % 28; int t2 = s / 28; int h = t2 % 28;
  const float* k = cw + c * 9;
  const float* xb = x + (size_t)s * 128 + c;
  float acc = cb[c];
  bool hm = h > 0, hp = h < 27, wm = w > 0, wp = w < 27;
  if (hm) {
    const float* r = xb - 28 * 128;
    if (wm) acc = fmaf(r[-128], k[0], acc);
    acc = fmaf(r[0], k[1], acc);
    if (wp) acc = fmaf(r[128], k[2], acc);
  }
  if (wm) acc = fmaf(xb[-128], k[3], acc);
  acc = fmaf(xb[0], k[4], acc);
  if (wp) acc = fmaf(xb[128], k[5], acc);
  if (hp) {
    const float* r = xb + 28 * 128;
    if (wm) acc = fmaf(r[-128], k[6], acc);
    acc = fmaf(r[0], k[7], acc);
    if (wp) acc = fmaf(r[128], k[8], acc);
  }
  out[(size_t)s * 128 + c] = acc;
}

// ---------------- K2: row filter (along W), line form ----------------------
__global__ __launch_bounds__(256) void k_rowfilt(const float* __restrict__ x,
    float* __restrict__ lo, float* __restrict__ hi) {
  int tid = threadIdx.x;
  int c = tid & 63;
  int line = blockIdx.x * 4 + (tid >> 6);     // line = b*28 + h, [0, 7168)
  const float* xp = x + (size_t)line * 28 * 128 + 64 + c;
  float v[28];
#pragma unroll
  for (int w = 0; w < 28; w++) v[w] = xp[w * 128];
  float* lp = lo + (size_t)line * 28 * 64 + c;
  float* hp = hi + (size_t)line * 28 * 64 + c;
#pragma unroll
  for (int w = 0; w < 28; w++) {
    float aLo = 0.f, aHi = 0.f;
#pragma unroll
    for (int t = 0; t < 13; t++) aLo = fmaf(F_H0[t], v[refl28(w - 6 + t)], aLo);
#pragma unroll
    for (int t = 0; t < 19; t++) aHi = fmaf(F_H1[t], v[refl28(w - 9 + t)], aHi);
    lp[w * 64] = aLo;
    hp[w * 64] = aHi;
  }
}

// ------- K3: column filter + q2c, line form (thread = (b, w2, c)) ----------
// unit = w2*256 + b  (4 units/block share w2 -> shared wll LDS tile)
__global__ __launch_bounds__(256) void k_colfilt(const float* __restrict__ lo,
    const float* __restrict__ hi, const float* __restrict__ wll,
    float* __restrict__ xl, float* __restrict__ xhr, float* __restrict__ xhi) {
  __shared__ float swll[3584];                 // [(h*2+woff)*64 + c]
  int tid = threadIdx.x;
  int w2 = blockIdx.x >> 6;                    // 896 blocks: 64 per w2
  // cooperative wll tile load (w = 2*w2, 2*w2+1; all h; all c)
  for (int j = tid; j < 3584; j += 256) {
    int cc = j & 63, t = j >> 6;               // t = h*2+woff
    int h = t >> 1, woff = t & 1;
    swll[j] = wll[cc * 784 + h * 28 + 2 * w2 + woff];
  }
  __syncthreads();
  int c = tid & 63;
  int unit = blockIdx.x * 4 + (tid >> 6);      // w2*256 + b
  int b = unit & 255;
  const int hs = 28 * 64;                      // h stride in lo/hi/xl
  int base_in = (b * 784 + 2 * w2) * 64 + c;
  // ---- low-pass row input ----
  float v0[28], v1[28];
#pragma unroll
  for (int h = 0; h < 28; h++) {
    v0[h] = lo[base_in + h * hs];
    v1[h] = lo[base_in + h * hs + 64];
  }
  // vll -> xl (with wll)
#pragma unroll
  for (int h = 0; h < 28; h++) {
    float a0 = 0.f, a1 = 0.f;
#pragma unroll
    for (int t = 0; t < 13; t++) {
      a0 = fmaf(F_H0[t], v0[refl28(h - 6 + t)], a0);
      a1 = fmaf(F_H0[t], v1[refl28(h - 6 + t)], a1);
    }
    int o = (b * 784 + h * 28 + 2 * w2) * 64 + c;
    xl[o]      = a0 * swll[(h * 2 + 0) * 64 + c];
    xl[o + 64] = a1 * swll[(h * 2 + 1) * 64 + c];
  }
  // vlh -> bands 0 (lhp), 5 (lhq)
  {
    float e0[28], e1[28];
#pragma unroll
    for (int h = 0; h < 28; h++) {
      float a0 = 0.f, a1 = 0.f;
#pragma unroll
      for (int t = 0; t < 19; t++) {
        a0 = fmaf(F_H1[t], v0[refl28(h - 9 + t)], a0);
        a1 = fmaf(F_H1[t], v1[refl28(h - 9 + t)], a1);
      }
      e0[h] = a0; e1[h] = a1;
    }
    int bb = (b * 6 * 196 + w2) * 64 + c;      // + band*12544 + i*896
#pragma unroll
    for (int i = 0; i < 14; i++) {
      float A = e0[2 * i], Bv = e1[2 * i], C = e0[2 * i + 1], D = e1[2 * i + 1];
      xhr[bb + 0 * 12544 + i * 896] = (A - D) * S2C;
      xhi[bb + 0 * 12544 + i * 896] = (Bv + C) * S2C;
      xhr[bb + 5 * 12544 + i * 896] = (A + D) * S2C;
      xhi[bb + 5 * 12544 + i * 896] = (Bv - C) * S2C;
    }
  }
  // ---- high-pass row input ----
#pragma unroll
  for (int h = 0; h < 28; h++) {
    v0[h] = hi[base_in + h * hs];
    v1[h] = hi[base_in + h * hs + 64];
  }
  // vhl -> bands 2 (hlp), 3 (hlq)
  {
    float e0[28], e1[28];
#pragma unroll
    for (int h = 0; h < 28; h++) {
      float a0 = 0.f, a1 = 0.f;
#pragma unroll
      for (int t = 0; t < 13; t++) {
        a0 = fmaf(F_H0[t], v0[refl28(h - 6 + t)], a0);
        a1 = fmaf(F_H0[t], v1[refl28(h - 6 + t)], a1);
      }
      e0[h] = a0; e1[h] = a1;
    }
    int bb = (b * 6 * 196 + w2) * 64 + c;
#pragma unroll
    for (int i = 0; i < 14; i++) {
      float A = e0[2 * i], Bv = e1[2 * i], C = e0[2 * i + 1], D = e1[2 * i + 1];
      xhr[bb + 2 * 12544 + i * 896] = (A - D) * S2C;
      xhi[bb + 2 * 12544 + i * 896] = (Bv + C) * S2C;
      xhr[bb + 3 * 12544 + i * 896] = (A + D) * S2C;
      xhi[bb + 3 * 12544 + i * 896] = (Bv - C) * S2C;
    }
  }
  // vhh -> bands 1 (hhp), 4 (hhq)
  {
    float e0[28], e1[28];
#pragma unroll
    for (int h = 0; h < 28; h++) {
      float a0 = 0.f, a1 = 0.f;
#pragma unroll
      for (int t = 0; t < 19; t++) {
        a0 = fmaf(F_H1[t], v0[refl28(h - 9 + t)], a0);
        a1 = fmaf(F_H1[t], v1[refl28(h - 9 + t)], a1);
      }
      e0[h] = a0; e1[h] = a1;
    }
    int bb = (b * 6 * 196 + w2) * 64 + c;
#pragma unroll
    for (int i = 0; i < 14; i++) {
      float A = e0[2 * i], Bv = e1[2 * i], C = e0[2 * i + 1], D = e1[2 * i + 1];
      xhr[bb + 1 * 12544 + i * 896] = (A - D) * S2C;
      xhi[bb + 1 * 12544 + i * 896] = (Bv + C) * S2C;
      xhr[bb + 4 * 12544 + i * 896] = (A + D) * S2C;
      xhi[bb + 4 * 12544 + i * 896] = (Bv - C) * S2C;
    }
  }
}

// ---------------- K4a: complex block-diag channel mix (in place) -----------
__global__ __launch_bounds__(256) void k_chmix(float* __restrict__ xhr,
    float* __restrict__ xhi,
    const float* __restrict__ w1, const float* __restrict__ w2,
    const float* __restrict__ b1, const float* __restrict__ b2) {
  __shared__ __align__(16) float sw1[2048];
  __shared__ __align__(16) float sw2[2048];
  __shared__ __align__(16) float sb1[128];
  __shared__ __align__(16) float sb2[128];
  int tid = threadIdx.x;
  for (int i = tid; i < 1024; i += 256) {
    int dk = i >> 2, blk = i & 3;
    int li = dk * 8 + blk * 2;
    sw1[li]     = w1[blk * 256 + dk];
    sw1[li + 1] = w1[1024 + blk * 256 + dk];
    sw2[li]     = w2[blk * 256 + dk];
    sw2[li + 1] = w2[1024 + blk * 256 + dk];
  }
  if (tid < 64) {
    int k = tid >> 2, blk = tid & 3;
    int li = k * 8 + blk * 2;
    sb1[li] = b1[blk * 16 + k]; sb1[li + 1] = b1[64 + blk * 16 + k];
    sb2[li] = b2[blk * 16 + k]; sb2[li + 1] = b2[64 + blk * 16 + k];
  }
  __syncthreads();
  int idx = blockIdx.x * 256 + tid;
  int blk = idx & 3;
  int p = idx >> 2;
  size_t base = (size_t)p * 64 + blk * 16;
  float xr[16], xi[16];
  const float4* pr = (const float4*)(xhr + base);
  const float4* pi = (const float4*)(xhi + base);
#pragma unroll
  for (int j = 0; j < 4; j++) {
    float4 a = pr[j];
    xr[4 * j] = a.x; xr[4 * j + 1] = a.y; xr[4 * j + 2] = a.z; xr[4 * j + 3] = a.w;
    float4 bb = pi[j];
    xi[4 * j] = bb.x; xi[4 * j + 1] = bb.y; xi[4 * j + 2] = bb.z; xi[4 * j + 3] = bb.w;
  }
  int wb = blk * 2;
  float yr[16], yi[16];
#pragma unroll
  for (int k = 0; k < 16; k++) {
    float2 bv = *(const float2*)(sb1 + k * 8 + wb);
    float ar = bv.x, ai = bv.y;
#pragma unroll
    for (int d = 0; d < 16; d++) {
      float2 wv = *(const float2*)(sw1 + (d * 16 + k) * 8 + wb);
      ar = fmaf(xr[d], wv.x, ar); ar = fmaf(-xi[d], wv.y, ar);
      ai = fmaf(xr[d], wv.y, ai); ai = fmaf(xi[d], wv.x, ai);
    }
    yr[k] = fmaxf(ar, 0.f); yi[k] = fmaxf(ai, 0.f);
  }
#pragma unroll
  for (int k = 0; k < 16; k++) {
    float2 bv = *(const float2*)(sb2 + k * 8 + wb);
    float ar = bv.x, ai = bv.y;
#pragma unroll
    for (int d = 0; d < 16; d++) {
      float2 wv = *(const float2*)(sw2 + (d * 16 + k) * 8 + wb);
      ar = fmaf(yr[d], wv.x, ar); ar = fmaf(-yi[d], wv.y, ar);
      ai = fmaf(yr[d], wv.y, ai); ai = fmaf(yi[d], wv.x, ai);
    }
    xr[k] = ar; xi[k] = ai;
  }
  float4* qr = (float4*)(xhr + base);
  float4* qi = (float4*)(xhi + base);
#pragma unroll
  for (int j = 0; j < 4; j++) {
    qr[j] = make_float4(xr[4 * j], xr[4 * j + 1], xr[4 * j + 2], xr[4 * j + 3]);
    qi[j] = make_float4(xi[4 * j], xi[4 * j + 1], xi[4 * j + 2], xi[4 * j + 3]);
  }
}

// ---------------- K4b: complex token mix over w2, per h2 (in place) --------
__global__ __launch_bounds__(256) void k_tokmix(float* __restrict__ xhr,
    float* __restrict__ xhi,
    const float* __restrict__ wt1, const float* __restrict__ wt2,
    const float* __restrict__ bt1, const float* __restrict__ bt2) {
  __shared__ __align__(16) float st1[5488];   // (h2*196+d*14+k)*2 + {r,i}
  __shared__ __align__(16) float st2[5488];
  __shared__ __align__(16) float sB1[392];
  __shared__ __align__(16) float sB2[392];
  int tid = threadIdx.x;
  for (int i = tid; i < 2744; i += 256) {
    st1[2 * i] = wt1[i]; st1[2 * i + 1] = wt1[2744 + i];
    st2[2 * i] = wt2[i]; st2[2 * i + 1] = wt2[2744 + i];
  }
  for (int i = tid; i < 196; i += 256) {
    sB1[2 * i] = bt1[i]; sB1[2 * i + 1] = bt1[196 + i];
    sB2[2 * i] = bt2[i]; sB2[2 * i + 1] = bt2[196 + i];
  }
  __syncthreads();
  int idx = blockIdx.x * 256 + tid;
  int c = idx & 63;
  int pp = idx >> 6;
  int h2 = pp % 14;
  int baseA = pp * 896 + c;
  int baseB = (pp + 10752) * 896 + c;
  float trA[14], tiA[14], trB[14], tiB[14];
#pragma unroll
  for (int d = 0; d < 14; d++) {
    trA[d] = xhr[baseA + d * 64]; tiA[d] = xhi[baseA + d * 64];
    trB[d] = xhr[baseB + d * 64]; tiB[d] = xhi[baseB + d * 64];
  }
  const float* w1 = st1 + h2 * 392;
  const float* w2 = st2 + h2 * 392;
  const float* bb1 = sB1 + h2 * 28;
  const float* bb2 = sB2 + h2 * 28;
  float mrA[14], miA[14], mrB[14], miB[14];
#pragma unroll
  for (int k = 0; k < 14; k++) {
    float br = bb1[2 * k], bi = bb1[2 * k + 1];
    float arA = br, aiA = bi, arB = br, aiB = bi;
#pragma unroll
    for (int d = 0; d < 14; d++) {
      float wr = w1[(d * 14 + k) * 2], wi = w1[(d * 14 + k) * 2 + 1];
      arA = fmaf(trA[d], wr, arA); arA = fmaf(-tiA[d], wi, arA);
      aiA = fmaf(trA[d], wi, aiA); aiA = fmaf(tiA[d], wr, aiA);
      arB = fmaf(trB[d], wr, arB); arB = fmaf(-tiB[d], wi, arB);
      aiB = fmaf(trB[d], wi, aiB); aiB = fmaf(tiB[d], wr, aiB);
    }
    mrA[k] = fmaxf(arA, 0.f); miA[k] = fmaxf(aiA, 0.f);
    mrB[k] = fmaxf(arB, 0.f); miB[k] = fmaxf(aiB, 0.f);
  }
#pragma unroll
  for (int k = 0; k < 14; k++) {
    float br = bb2[2 * k], bi = bb2[2 * k + 1];
    float arA = br, aiA = bi, arB = br, aiB = bi;
#pragma unroll
    for (int d = 0; d < 14; d++) {
      float wr = w2[(d * 14 + k) * 2], wi = w2[(d * 14 + k) * 2 + 1];
      arA = fmaf(mrA[d], wr, arA); arA = fmaf(-miA[d], wi, arA);
      aiA = fmaf(mrA[d], wi, aiA); aiA = fmaf(miA[d], wr, aiA);
      arB = fmaf(mrB[d], wr, arB); arB = fmaf(-miB[d], wi, arB);
      aiB = fmaf(mrB[d], wi, aiB); aiB = fmaf(miB[d], wr, aiB);
    }
    xhr[baseA + k * 64] = arA; xhi[baseA + k * 64] = aiA;
    xhr[baseB + k * 64] = arB; xhi[baseB + k * 64] = aiB;
  }
}

// -------- K5: inverse column filter, line form (thread = (b, w, c)) --------
__global__ __launch_bounds__(256) void k_invcol(const float* __restrict__ xl,
    const float* __restrict__ xhr, const float* __restrict__ xhi,
    float* __restrict__ lo2, float* __restrict__ hi2) {
  int tid = threadIdx.x;
  int c = tid & 63;
  int line = blockIdx.x * 4 + (tid >> 6);      // line = b*28 + w
  int w = line % 28, b = line / 28;
  int w2 = w >> 1, pw = w & 1;
  const int hs = 28 * 64;
  int sp = (b * 784 + w) * 64 + c;             // spatial base (h stride hs)
  int bb = (b * 6 * 196 + w2) * 64 + c;        // band base (+band*12544+i*896)
  // ---- pass 1: lo2 = g0*xl + g1*(s2*lhf) ----
  {
    float xlv[28], lhf[28];
#pragma unroll
    for (int h = 0; h < 28; h++) xlv[h] = xl[sp + h * hs];
    const float* p0r = xhr + bb + 0 * 12544;
    const float* p0i = xhi + bb + 0 * 12544;
    const float* p5r = xhr + bb + 5 * 12544;
    const float* p5i = xhi + bb + 5 * 12544;
#pragma unroll
    for (int i = 0; i < 14; i++) {
      float y0r = p0r[i * 896], y0i = p0i[i * 896];
      float y5r = p5r[i * 896], y5i = p5i[i * 896];
      float top, bot;
      if (pw) { top = y0i + y5i; bot = y5r - y0r; }
      else    { top = y0r + y5r; bot = y0i - y5i; }
      lhf[2 * i] = top * S2C; lhf[2 * i + 1] = bot * S2C;
    }
#pragma unroll
    for (int h = 0; h < 28; h++) {
      float acc = 0.f;
#pragma unroll
      for (int t = 0; t < 19; t++) acc = fmaf(F_G0[t], xlv[refl28(h - 9 + t)], acc);
#pragma unroll
      for (int t = 0; t < 13; t++) acc = fmaf(F_G1[t], lhf[refl28(h - 6 + t)], acc);
      lo2[sp + h * hs] = acc;
    }
  }
  // ---- pass 2: hi2 = g0*(s2*hlC) + g1*(s2*hhD) ----
  {
    float hlC[28], hhD[28];
    const float* p2r = xhr + bb + 2 * 12544;
    const float* p2i = xhi + bb + 2 * 12544;
    const float* p3r = xhr + bb + 3 * 12544;
    const float* p3i = xhi + bb + 3 * 12544;
#pragma unroll
    for (int i = 0; i < 14; i++) {
      float y0r = p2r[i * 896], y0i = p2i[i * 896];
      float y5r = p3r[i * 896], y5i = p3i[i * 896];
      float top, bot;
      if (pw) { top = y0i + y5i; bot = y5r - y0r; }
      else    { top = y0r + y5r; bot = y0i - y5i; }
      hlC[2 * i] = top * S2C; hlC[2 * i + 1] = bot * S2C;
    }
    const float* p1r = xhr + bb + 1 * 12544;
    const float* p1i = xhi + bb + 1 * 12544;
    const float* p4r = xhr + bb + 4 * 12544;
    const float* p4i = xhi + bb + 4 * 12544;
#pragma unroll
    for (int i = 0; i < 14; i++) {
      float y0r = p1r[i * 896], y0i = p1i[i * 896];
      float y5r = p4r[i * 896], y5i = p4i[i * 896];
      float top, bot;
      if (pw) { top = y0i + y5i; bot = y5r - y0r; }
      else    { top = y0r + y5r; bot = y0i - y5i; }
      hhD[2 * i] = top * S2C; hhD[2 * i + 1] = bot * S2C;
    }
#pragma unroll
    for (int h = 0; h < 28; h++) {
      float acc = 0.f;
#pragma unroll
      for (int t = 0; t < 19; t++) acc = fmaf(F_G0[t], hlC[refl28(h - 9 + t)], acc);
#pragma unroll
      for (int t = 0; t < 13; t++) acc = fmaf(F_G1[t], hhD[refl28(h - 6 + t)], acc);
      hi2[sp + h * hs] = acc;
    }
  }
}

// ---------------- K6: inverse row filter, line form ------------------------
__global__ __launch_bounds__(256) void k_invrow(const float* __restrict__ lo2,
    const float* __restrict__ hi2, float* __restrict__ out) {
  int tid = threadIdx.x;
  int c = tid & 63;
  int line = blockIdx.x * 4 + (tid >> 6);      // line = b*28 + h
  const float* lr = lo2 + (size_t)line * 28 * 64 + c;
  const float* hr = hi2 + (size_t)line * 28 * 64 + c;
  float vl[28], vh[28];
#pragma unroll
  for (int w = 0; w < 28; w++) { vl[w] = lr[w * 64]; vh[w] = hr[w * 64]; }
  float* op = out + (size_t)line * 28 * 128 + 64 + c;
#pragma unroll
  for (int w = 0; w < 28; w++) {
    float acc = 0.f;
#pragma unroll
    for (int t = 0; t < 19; t++) acc = fmaf(F_G0[t], vl[refl28(w - 9 + t)], acc);
#pragma unroll
    for (int t = 0; t < 13; t++) acc = fmaf(F_G1[t], vh[refl28(w - 6 + t)], acc);
    op[w * 128] = acc;
  }
}

// ---------------------------------------------------------------------------
extern "C" void kernel_launch(void* const* d_in, const int* in_sizes, int n_in,
                              void* d_out, int out_size, void* d_ws, size_t ws_size,
                              hipStream_t stream) {
  const float* x    = (const float*)d_in[0];
  const float* cw   = (const float*)d_in[1];
  const float* cb   = (const float*)d_in[2];
  const float* wll  = (const float*)d_in[3];
  const float* wlh1 = (const float*)d_in[4];
  const float* wlh2 = (const float*)d_in[5];
  const float* blh1 = (const float*)d_in[6];
  const float* blh2 = (const float*)d_in[7];
  const float* wt1  = (const float*)d_in[8];
  const float* wt2  = (const float*)d_in[9];
  const float* bt1  = (const float*)d_in[10];
  const float* bt2  = (const float*)d_in[11];
  float* out = (float*)d_out;
  float* ws = (float*)d_ws;

  const size_t NSP = (size_t)256 * 784 * 64;     // 12,845,056
  const size_t NXH = (size_t)256 * 6 * 196 * 64; // 19,267,584
  float* lo  = ws;              // reused as lo2 after k_colfilt consumes it
  float* hi  = lo + NSP;        // reused as hi2
  float* xl  = hi + NSP;
  float* xhr = xl + NSP;
  float* xhi = xhr + NXH;       // total 308.3 MB

  dim3 blk(256);
  k_dwconv <<<50176, blk, 0, stream>>>(x, cw, cb, out);
  k_rowfilt<<<1792,  blk, 0, stream>>>(x, lo, hi);
  k_colfilt<<<896,   blk, 0, stream>>>(lo, hi, wll, xl, xhr, xhi);
  k_chmix  <<<4704,  blk, 0, stream>>>(xhr, xhi, wlh1, wlh2, blh1, blh2);
  k_tokmix <<<2688,  blk, 0, stream>>>(xhr, xhi, wt1, wt2, bt1, bt2);
  k_invcol <<<1792,  blk, 0, stream>>>(xl, xhr, xhi, lo, hi);
  k_invrow <<<1792,  blk, 0, stream>>>(lo, hi, out);
  (void)in_sizes; (void)n_in; (void)out_size; (void)ws_size;
}